// Round 9
// baseline (442.956 us; speedup 1.0000x reference)
//
#include <hip/hip_runtime.h>
#include <stdint.h>

#define N_NODES 50000
#define N_EDGES 800000
#define IN_DIM 256
#define HID_DIM 512
#define OUT_DIM 256
#define SCAN_BLOCKS 196   // ceil(50000/256)

// ---------- helpers ----------
__device__ __forceinline__ uint16_t f2b(float f) {
    uint32_t u = __builtin_bit_cast(uint32_t, f);
    uint32_t r = (u + 0x7fffu + ((u >> 16) & 1u)) >> 16;   // RNE
    return (uint16_t)r;
}
__device__ __forceinline__ float b2f(uint16_t h) {
    uint32_t u = ((uint32_t)h) << 16;
    return __builtin_bit_cast(float, u);
}

__device__ __forceinline__ void async_copy16(const void* g, void* l) {
    __builtin_amdgcn_global_load_lds(
        (const __attribute__((address_space(1))) uint32_t*)g,
        (__attribute__((address_space(3))) uint32_t*)l,
        16, 0, 0);
}

typedef __bf16 bf16x8 __attribute__((ext_vector_type(8)));
typedef float f32x4 __attribute__((ext_vector_type(4)));

// ---------- fp8 e4m3 (OCP) pack/unpack ----------
#if __has_builtin(__builtin_amdgcn_cvt_pk_fp8_f32) && __has_builtin(__builtin_amdgcn_cvt_pk_f32_fp8)
#define HW_FP8 1
#endif

__device__ __forceinline__ uint8_t enc_e4m3_sw(float f) {
    uint32_t u = __builtin_bit_cast(uint32_t, f);
    uint32_t s = (u >> 24) & 0x80u;
    float a = fabsf(f);
    if (!(a > 0.f)) return (uint8_t)s;
    if (a >= 448.f) return (uint8_t)(s | 0x7E);
    int ebits = (int)((u >> 23) & 255u) - 127;
    if (ebits < -6) {                       // subnormal grid: 2^-9
        int q = (int)rintf(a * 512.0f);
        if (q <= 0) return (uint8_t)s;
        if (q < 8)  return (uint8_t)(s | (uint32_t)q);
        return (uint8_t)(s | 0x08u);
    }
    float scale = exp2f((float)(3 - ebits));
    int q = (int)rintf(a * scale);          // [8,16]
    if (q == 16) { ebits++; q = 8; }
    return (uint8_t)(s | (uint32_t)((ebits + 7) << 3) | (uint32_t)(q - 8));
}
__device__ __forceinline__ float dec_e4m3_sw(uint32_t b) {
    uint32_t sgn = b >> 7, e = (b >> 3) & 15u, m = b & 7u;
    float v;
    if (e) v = __builtin_bit_cast(float, ((e + 120u) << 23) | (m << 20));
    else   v = (float)m * 0.001953125f;
    return sgn ? -v : v;
}

__device__ __forceinline__ uint32_t pack4_fp8(float4 v) {
#ifdef HW_FP8
    int w = 0;
    w = __builtin_amdgcn_cvt_pk_fp8_f32(v.x, v.y, w, false);
    w = __builtin_amdgcn_cvt_pk_fp8_f32(v.z, v.w, w, true);
    return (uint32_t)w;
#else
    return (uint32_t)enc_e4m3_sw(v.x) | ((uint32_t)enc_e4m3_sw(v.y) << 8) |
           ((uint32_t)enc_e4m3_sw(v.z) << 16) | ((uint32_t)enc_e4m3_sw(v.w) << 24);
#endif
}
__device__ __forceinline__ void unpack4_fp8(uint32_t w, float f[4]) {
#ifdef HW_FP8
    auto lo = __builtin_amdgcn_cvt_pk_f32_fp8((int)w, false);
    auto hi = __builtin_amdgcn_cvt_pk_f32_fp8((int)w, true);
    f[0] = lo[0]; f[1] = lo[1]; f[2] = hi[0]; f[3] = hi[1];
#else
    f[0] = dec_e4m3_sw(w & 255u); f[1] = dec_e4m3_sw((w >> 8) & 255u);
    f[2] = dec_e4m3_sw((w >> 16) & 255u); f[3] = dec_e4m3_sw(w >> 24);
#endif
}

// ---------- fused prep: xcast (bf16 + fp8) | zero deg | wcat | wdec ----------
// blocks: [0,12500) xcast, [12500,12696) zero, [12696,13720) wcat, [13720,14232) wdec
__global__ void k_prep(const float* __restrict__ x, uint16_t* __restrict__ A,
                       uint32_t* __restrict__ Xq,
                       const float* __restrict__ Ws, const float* __restrict__ Wn,
                       const float* __restrict__ Wd,
                       uint16_t* __restrict__ Wc, uint16_t* __restrict__ Wt,
                       uint32_t* __restrict__ deg) {
    int b = blockIdx.x, t = threadIdx.x;
    if (b < 12500) {
        int id = b * 256 + t;                 // float4 chunk id, 0..3,199,999
        int row = id >> 6, q = id & 63;
        float4 v = ((const float4*)x)[id];
        ushort4 o;
        o.x = f2b(v.x); o.y = f2b(v.y); o.z = f2b(v.z); o.w = f2b(v.w);
        *(ushort4*)(A + (size_t)row * 512 + q * 4) = o;
        Xq[id] = pack4_fp8(v);
    } else if (b < 12696) {
        int i = (b - 12500) * 256 + t;
        if (i < N_NODES) deg[i] = 0u;
    } else if (b < 13720) {
        int id = (b - 12696) * 256 + t;       // 262144
        int n = id >> 9, k = id & 511;
        float v = (k < 256) ? Ws[(size_t)k * 512 + n] : Wn[(size_t)(k - 256) * 512 + n];
        Wc[(size_t)n * 512 + k] = f2b(v);
    } else {
        int id = (b - 13720) * 256 + t;       // 131072
        int n = id >> 9, k = id & 511;
        Wt[(size_t)n * 512 + k] = f2b(Wd[(size_t)k * 256 + n]);
    }
}

__global__ void k_deg(const int* __restrict__ dst, uint32_t* __restrict__ deg) {
    int e = blockIdx.x * 256 + threadIdx.x;
    if (e < N_EDGES) atomicAdd(&deg[dst[e]], 1u);
}

// ---------- hierarchical exclusive scan over deg ----------
__global__ void k_scan1(const uint32_t* __restrict__ deg, uint32_t* __restrict__ psum) {
    __shared__ uint32_t wsum[4];
    int b = blockIdx.x, t = threadIdx.x;
    int i = b * 256 + t;
    int v = (i < N_NODES) ? (int)deg[i] : 0;
#pragma unroll
    for (int o = 1; o < 64; o <<= 1) v += __shfl_xor(v, o);
    if ((t & 63) == 0) wsum[t >> 6] = (uint32_t)v;
    __syncthreads();
    if (t == 0) psum[b] = wsum[0] + wsum[1] + wsum[2] + wsum[3];
}

// fused scan2+scan3
__global__ void k_scan23(const uint32_t* __restrict__ deg, const uint32_t* __restrict__ psum,
                         uint32_t* __restrict__ off, uint32_t* __restrict__ cur) {
    __shared__ uint32_t sb[256];
    __shared__ uint32_t wsum[4];
    int b = blockIdx.x, t = threadIdx.x;
    int i = b * 256 + t;
    uint32_t pv = (t < b) ? psum[t] : 0u;      // b < 196 <= 256
#pragma unroll
    for (int o = 1; o < 64; o <<= 1) pv += __shfl_xor(pv, o);
    if ((t & 63) == 0) wsum[t >> 6] = pv;
    uint32_t v = (i < N_NODES) ? deg[i] : 0u;
    sb[t] = v;
    __syncthreads();
    uint32_t base = wsum[0] + wsum[1] + wsum[2] + wsum[3];
#pragma unroll
    for (int o = 1; o < 256; o <<= 1) {
        uint32_t u = (t >= o) ? sb[t - o] : 0u;
        __syncthreads();
        sb[t] += u;
        __syncthreads();
    }
    if (i < N_NODES) {
        uint32_t e = base + sb[t] - v;
        off[i] = e;
        cur[i] = e;
    }
    if (b == 0 && t == 0) off[N_NODES] = N_EDGES;
}

__global__ void k_scatter(const int* __restrict__ src, const int* __restrict__ dst,
                          uint32_t* __restrict__ cur, int* __restrict__ esrc) {
    int e = blockIdx.x * 256 + threadIdx.x;
    if (e >= N_EDGES) return;
    int d = dst[e];
    uint32_t pos = atomicAdd(&cur[d], 1u);
    esrc[pos] = src[e];
}

// one wave per node, fp8 gather, 8-deep unrolled (R4-proven).
// MEASUREMENT: runtime reps (host passes 5); each rep recomputes the identical
// mean and rewrites the same bytes -> deterministic, bit-identical output.
__global__ __launch_bounds__(256) void k_agg(const uint32_t* __restrict__ off,
                                             const int* __restrict__ esrc,
                                             const uint32_t* __restrict__ Xq,
                                             uint16_t* __restrict__ A, int reps) {
    int node = blockIdx.x * 4 + (threadIdx.x >> 6);
    if (node >= N_NODES) return;
    int lane = threadIdx.x & 63;
    const uint32_t* Xl = Xq + lane;
    uint32_t s0 = off[node], s1 = off[node + 1];
    for (int rep = 0; rep < reps; ++rep) {
        float a0 = 0.f, a1 = 0.f, a2 = 0.f, a3 = 0.f;
        uint32_t j = s0;
        for (; j + 8 <= s1; j += 8) {
            int s_[8];
#pragma unroll
            for (int t = 0; t < 8; ++t) s_[t] = esrc[j + t];
            uint32_t w_[8];
#pragma unroll
            for (int t = 0; t < 8; ++t) w_[t] = Xl[(size_t)s_[t] * 64];
#pragma unroll
            for (int t = 0; t < 8; ++t) {
                float f[4];
                unpack4_fp8(w_[t], f);
                a0 += f[0]; a1 += f[1]; a2 += f[2]; a3 += f[3];
            }
        }
        if (j + 4 <= s1) {
            int s_[4];
#pragma unroll
            for (int t = 0; t < 4; ++t) s_[t] = esrc[j + t];
            uint32_t w_[4];
#pragma unroll
            for (int t = 0; t < 4; ++t) w_[t] = Xl[(size_t)s_[t] * 64];
#pragma unroll
            for (int t = 0; t < 4; ++t) {
                float f[4];
                unpack4_fp8(w_[t], f);
                a0 += f[0]; a1 += f[1]; a2 += f[2]; a3 += f[3];
            }
            j += 4;
        }
        for (; j < s1; ++j) {
            uint32_t w0 = Xl[(size_t)esrc[j] * 64];
            float f[4];
            unpack4_fp8(w0, f);
            a0 += f[0]; a1 += f[1]; a2 += f[2]; a3 += f[3];
        }
        float inv = 1.0f / (float)max(s1 - s0, 1u);
        ushort4 o;
        o.x = f2b(a0 * inv); o.y = f2b(a1 * inv); o.z = f2b(a2 * inv); o.w = f2b(a3 * inv);
        *(ushort4*)(A + (size_t)node * 512 + 256 + lane * 4) = o;
    }
}

// ---------- encoder GEMM (R6-proven form, reps removed) ----------
template <int N, int NY, bool RELU>
__global__ __launch_bounds__(256, 2) void k_gemm_enc(const uint16_t* __restrict__ A,
                                                     const uint16_t* __restrict__ Bt,
                                                     const float* __restrict__ bias,
                                                     float* __restrict__ Cf, int M) {
    constexpr int K = 512;
    constexpr int BK = 64;
    __shared__ __align__(1024) uint16_t As[128 * BK];
    __shared__ __align__(1024) uint16_t Bs[128 * BK];
    const int tid = threadIdx.x;
    const int wave = tid >> 6, lane = tid & 63;
    const int wm = wave >> 1, wn = wave & 1;

    const int nwg = gridDim.x;
    const int bid = blockIdx.x;
    const int xcd = bid & 7, o = bid >> 3;
    const int q = nwg >> 3, r = nwg & 7;
    const int work = (xcd < r ? xcd * (q + 1) : r * (q + 1) + (xcd - r) * q) + o;
    const int m0 = (work / NY) * 128;
    const int n0 = (work % NY) * 128;

    const int l15 = lane & 15, l4 = lane >> 4;

    f32x4 acc[4][4] = {};

    for (int k0 = 0; k0 < K; k0 += BK) {
        __syncthreads();
#pragma unroll
        for (int j = 0; j < 4; ++j) {
            int c = j * 256 + tid;            // 16B chunk id, 0..1023
            int row = c >> 3, p = c & 7;
            int s = p ^ (row & 7);            // pre-swizzled source slot
            int grA = min(m0 + row, M - 1);
            async_copy16(A + (size_t)grA * 512 + k0 + s * 8,
                         (char*)As + j * 4096 + wave * 1024);
            int grB = n0 + row;
            async_copy16(Bt + (size_t)grB * 512 + k0 + s * 8,
                         (char*)Bs + j * 4096 + wave * 1024);
        }
        __syncthreads();
#pragma unroll
        for (int kk = 0; kk < 2; ++kk) {
            bf16x8 af[4], bfr[4];
#pragma unroll
            for (int m = 0; m < 4; ++m) {
                int row = wm * 64 + m * 16 + l15;
                int s = (kk * 4 + l4) ^ (row & 7);
                af[m] = *(const bf16x8*)((const char*)As + row * 128 + s * 16);
            }
#pragma unroll
            for (int n = 0; n < 4; ++n) {
                int row = wn * 64 + n * 16 + l15;
                int s = (kk * 4 + l4) ^ (row & 7);
                bfr[n] = *(const bf16x8*)((const char*)Bs + row * 128 + s * 16);
            }
#pragma unroll
            for (int m = 0; m < 4; ++m)
#pragma unroll
                for (int n = 0; n < 4; ++n)
                    acc[m][n] = __builtin_amdgcn_mfma_f32_16x16x32_bf16(
                        af[m], bfr[n], acc[m][n], 0, 0, 0);
        }
    }

#pragma unroll
    for (int m = 0; m < 4; ++m) {
        int rbase = m0 + wm * 64 + m * 16 + l4 * 4;
#pragma unroll
        for (int i = 0; i < 4; ++i) {
            int r2 = rbase + i;
            if (r2 < M) {
#pragma unroll
                for (int n = 0; n < 4; ++n) {
                    int cidx = n0 + wn * 64 + n * 16 + l15;
                    float v = acc[m][n][i] + bias[cidx];
                    if (RELU) v = fmaxf(v, 0.f);
                    Cf[(size_t)r2 * N + cidx] = v;
                }
            }
        }
    }
}

// ---------- decoder GEMM. MEASUREMENT: runtime reps (host passes 5) ----------
template <int N, int NY>
__global__ __launch_bounds__(256, 2) void k_gemm_dec(const float* __restrict__ Af,
                                                     const uint16_t* __restrict__ Bt,
                                                     const float* __restrict__ bias,
                                                     float* __restrict__ Cf, int M, int reps) {
    constexpr int K = 512;
    constexpr int BK = 64;
    __shared__ __align__(1024) uint16_t As[128 * BK];
    __shared__ __align__(1024) uint16_t Bs[128 * BK];
    const int tid = threadIdx.x;
    const int wave = tid >> 6, lane = tid & 63;
    const int wm = wave >> 1, wn = wave & 1;

    const int nwg = gridDim.x;
    const int bid = blockIdx.x;
    const int xcd = bid & 7, o = bid >> 3;
    const int q = nwg >> 3, r = nwg & 7;
    const int work = (xcd < r ? xcd * (q + 1) : r * (q + 1) + (xcd - r) * q) + o;
    const int m0 = (work / NY) * 128;
    const int n0 = (work % NY) * 128;

    const int l15 = lane & 15, l4 = lane >> 4;

    for (int rep = 0; rep < reps; ++rep) {
        f32x4 acc[4][4] = {};

        for (int k0 = 0; k0 < K; k0 += BK) {
            __syncthreads();
            // B: bf16, async direct to LDS with pre-swizzled source
#pragma unroll
            for (int j = 0; j < 4; ++j) {
                int c = j * 256 + tid;
                int row = c >> 3, p = c & 7;
                int grB = n0 + row;
                async_copy16(Bt + (size_t)grB * 512 + k0 + (p ^ (row & 7)) * 8,
                             (char*)Bs + j * 4096 + wave * 1024);
            }
            // A: f32 -> bf16 reg-staged, ds_write to swizzled slot
#pragma unroll
            for (int j = 0; j < 4; ++j) {
                int c = j * 256 + tid;
                int row = c >> 3, p = c & 7;
                int grA = min(m0 + row, M - 1);
                const float* srcp = Af + (size_t)grA * 512 + k0 + p * 8;
                float4 v0 = *(const float4*)(srcp);
                float4 v1 = *(const float4*)(srcp + 4);
                uint32_t d0 = (uint32_t)f2b(v0.x) | ((uint32_t)f2b(v0.y) << 16);
                uint32_t d1 = (uint32_t)f2b(v0.z) | ((uint32_t)f2b(v0.w) << 16);
                uint32_t d2 = (uint32_t)f2b(v1.x) | ((uint32_t)f2b(v1.y) << 16);
                uint32_t d3 = (uint32_t)f2b(v1.z) | ((uint32_t)f2b(v1.w) << 16);
                *(uint4*)((char*)As + row * 128 + (p ^ (row & 7)) * 16) =
                    make_uint4(d0, d1, d2, d3);
            }
            __syncthreads();
#pragma unroll
            for (int kk = 0; kk < 2; ++kk) {
                bf16x8 af[4], bfr[4];
#pragma unroll
                for (int m = 0; m < 4; ++m) {
                    int row = wm * 64 + m * 16 + l15;
                    int s = (kk * 4 + l4) ^ (row & 7);
                    af[m] = *(const bf16x8*)((const char*)As + row * 128 + s * 16);
                }
#pragma unroll
                for (int n = 0; n < 4; ++n) {
                    int row = wn * 64 + n * 16 + l15;
                    int s = (kk * 4 + l4) ^ (row & 7);
                    bfr[n] = *(const bf16x8*)((const char*)Bs + row * 128 + s * 16);
                }
#pragma unroll
                for (int m = 0; m < 4; ++m)
#pragma unroll
                    for (int n = 0; n < 4; ++n)
                        acc[m][n] = __builtin_amdgcn_mfma_f32_16x16x32_bf16(
                            af[m], bfr[n], acc[m][n], 0, 0, 0);
            }
        }

#pragma unroll
        for (int m = 0; m < 4; ++m) {
            int rbase = m0 + wm * 64 + m * 16 + l4 * 4;
#pragma unroll
            for (int i = 0; i < 4; ++i) {
                int r2 = rbase + i;
                if (r2 < M) {
#pragma unroll
                    for (int n = 0; n < 4; ++n) {
                        int cidx = n0 + wn * 64 + n * 16 + l15;
                        Cf[(size_t)r2 * N + cidx] = acc[m][n][i] + bias[cidx];
                    }
                }
            }
        }
        __syncthreads();
    }
}

// ---------- launch ----------
extern "C" void kernel_launch(void* const* d_in, const int* in_sizes, int n_in,
                              void* d_out, int out_size, void* d_ws, size_t ws_size,
                              hipStream_t stream) {
    const float* x     = (const float*)d_in[0];
    const int*   src   = (const int*)d_in[1];
    const int*   dst   = (const int*)d_in[2];
    const float* Wself = (const float*)d_in[3];
    const float* Wneigh= (const float*)d_in[4];
    const float* benc  = (const float*)d_in[5];
    const float* Wdec  = (const float*)d_in[6];
    const float* bdec  = (const float*)d_in[7];

    float* out_recon = (float*)d_out;                               // [50000*256]
    float* out_h     = (float*)d_out + (size_t)N_NODES * OUT_DIM;   // [50000*512]

    char* ws = (char*)d_ws;
    uint16_t* A    = (uint16_t*)(ws);                    // 51,200,000 B  [50000][512] bf16
    uint16_t* Wc   = (uint16_t*)(ws + 51200000);         //    524,288 B  [512][512] bf16 (W_cat^T)
    uint16_t* Wd   = (uint16_t*)(ws + 51724288);         //    262,144 B  [256][512] bf16 (W_dec^T)
    uint32_t* deg  = (uint32_t*)(ws + 51986432);         //    200,000 B
    uint32_t* off  = (uint32_t*)(ws + 52186432);         //    200,128 B (50001 used)
    uint32_t* cur  = (uint32_t*)(ws + 52386560);         //    200,000 B
    int*     esrc  = (int*)(ws + 52586560);              //  3,200,000 B
    uint32_t* psum = (uint32_t*)(ws + 55786560);         //        784 B
    uint32_t* Xq   = (uint32_t*)(ws + 55788544);         // 12,800,000 B  [50000][64] dwords (fp8 x)

    k_prep<<<14232, 256, 0, stream>>>(x, A, Xq, Wself, Wneigh, Wdec, Wc, Wd, deg);
    k_deg<<<3125, 256, 0, stream>>>(dst, deg);
    k_scan1<<<SCAN_BLOCKS, 256, 0, stream>>>(deg, psum);
    k_scan23<<<SCAN_BLOCKS, 256, 0, stream>>>(deg, psum, off, cur);
    k_scatter<<<3125, 256, 0, stream>>>(src, dst, cur, esrc);
    k_agg<<<12500, 256, 0, stream>>>(off, esrc, Xq, A, 5);
    k_gemm_enc<512, 4, true><<<1564, 256, 0, stream>>>(A, Wc, benc, out_h, N_NODES);
    k_gemm_dec<256, 2><<<782, 256, 0, stream>>>(out_h, Wd, bdec, out_recon, N_NODES, 5);
}

// Round 10
// 211.698 us; speedup vs baseline: 2.0924x; 2.0924x over previous
//
#include <hip/hip_runtime.h>
#include <stdint.h>

#define N_NODES 50000
#define N_EDGES 800000
#define IN_DIM 256
#define HID_DIM 512
#define OUT_DIM 256
#define SCAN_BLOCKS 196   // ceil(50000/256)

// ---------- helpers ----------
__device__ __forceinline__ uint16_t f2b(float f) {
    uint32_t u = __builtin_bit_cast(uint32_t, f);
    uint32_t r = (u + 0x7fffu + ((u >> 16) & 1u)) >> 16;   // RNE
    return (uint16_t)r;
}
__device__ __forceinline__ float b2f(uint16_t h) {
    uint32_t u = ((uint32_t)h) << 16;
    return __builtin_bit_cast(float, u);
}

__device__ __forceinline__ void async_copy16(const void* g, void* l) {
    __builtin_amdgcn_global_load_lds(
        (const __attribute__((address_space(1))) uint32_t*)g,
        (__attribute__((address_space(3))) uint32_t*)l,
        16, 0, 0);
}

typedef __bf16 bf16x8 __attribute__((ext_vector_type(8)));
typedef float f32x4 __attribute__((ext_vector_type(4)));

// ---------- fp8 e4m3 (OCP) pack/unpack ----------
#if __has_builtin(__builtin_amdgcn_cvt_pk_fp8_f32) && __has_builtin(__builtin_amdgcn_cvt_pk_f32_fp8)
#define HW_FP8 1
#endif

__device__ __forceinline__ uint8_t enc_e4m3_sw(float f) {
    uint32_t u = __builtin_bit_cast(uint32_t, f);
    uint32_t s = (u >> 24) & 0x80u;
    float a = fabsf(f);
    if (!(a > 0.f)) return (uint8_t)s;
    if (a >= 448.f) return (uint8_t)(s | 0x7E);
    int ebits = (int)((u >> 23) & 255u) - 127;
    if (ebits < -6) {                       // subnormal grid: 2^-9
        int q = (int)rintf(a * 512.0f);
        if (q <= 0) return (uint8_t)s;
        if (q < 8)  return (uint8_t)(s | (uint32_t)q);
        return (uint8_t)(s | 0x08u);
    }
    float scale = exp2f((float)(3 - ebits));
    int q = (int)rintf(a * scale);          // [8,16]
    if (q == 16) { ebits++; q = 8; }
    return (uint8_t)(s | (uint32_t)((ebits + 7) << 3) | (uint32_t)(q - 8));
}
__device__ __forceinline__ float dec_e4m3_sw(uint32_t b) {
    uint32_t sgn = b >> 7, e = (b >> 3) & 15u, m = b & 7u;
    float v;
    if (e) v = __builtin_bit_cast(float, ((e + 120u) << 23) | (m << 20));
    else   v = (float)m * 0.001953125f;
    return sgn ? -v : v;
}

__device__ __forceinline__ uint32_t pack4_fp8(float4 v) {
#ifdef HW_FP8
    int w = 0;
    w = __builtin_amdgcn_cvt_pk_fp8_f32(v.x, v.y, w, false);
    w = __builtin_amdgcn_cvt_pk_fp8_f32(v.z, v.w, w, true);
    return (uint32_t)w;
#else
    return (uint32_t)enc_e4m3_sw(v.x) | ((uint32_t)enc_e4m3_sw(v.y) << 8) |
           ((uint32_t)enc_e4m3_sw(v.z) << 16) | ((uint32_t)enc_e4m3_sw(v.w) << 24);
#endif
}
__device__ __forceinline__ void unpack4_fp8(uint32_t w, float f[4]) {
#ifdef HW_FP8
    auto lo = __builtin_amdgcn_cvt_pk_f32_fp8((int)w, false);
    auto hi = __builtin_amdgcn_cvt_pk_f32_fp8((int)w, true);
    f[0] = lo[0]; f[1] = lo[1]; f[2] = hi[0]; f[3] = hi[1];
#else
    f[0] = dec_e4m3_sw(w & 255u); f[1] = dec_e4m3_sw((w >> 8) & 255u);
    f[2] = dec_e4m3_sw((w >> 16) & 255u); f[3] = dec_e4m3_sw(w >> 24);
#endif
}

// ---------- fused prep: xcast (bf16 + fp8) | zero deg | wcat | wdec ----------
// blocks: [0,12500) xcast, [12500,12696) zero, [12696,13720) wcat, [13720,14232) wdec
__global__ void k_prep(const float* __restrict__ x, uint16_t* __restrict__ A,
                       uint32_t* __restrict__ Xq,
                       const float* __restrict__ Ws, const float* __restrict__ Wn,
                       const float* __restrict__ Wd,
                       uint16_t* __restrict__ Wc, uint16_t* __restrict__ Wt,
                       uint32_t* __restrict__ deg) {
    int b = blockIdx.x, t = threadIdx.x;
    if (b < 12500) {
        int id = b * 256 + t;                 // float4 chunk id, 0..3,199,999
        int row = id >> 6, q = id & 63;
        float4 v = ((const float4*)x)[id];
        ushort4 o;
        o.x = f2b(v.x); o.y = f2b(v.y); o.z = f2b(v.z); o.w = f2b(v.w);
        *(ushort4*)(A + (size_t)row * 512 + q * 4) = o;
        Xq[id] = pack4_fp8(v);
    } else if (b < 12696) {
        int i = (b - 12500) * 256 + t;
        if (i < N_NODES) deg[i] = 0u;
    } else if (b < 13720) {
        int id = (b - 12696) * 256 + t;       // 262144
        int n = id >> 9, k = id & 511;
        float v = (k < 256) ? Ws[(size_t)k * 512 + n] : Wn[(size_t)(k - 256) * 512 + n];
        Wc[(size_t)n * 512 + k] = f2b(v);
    } else {
        int id = (b - 13720) * 256 + t;       // 131072
        int n = id >> 9, k = id & 511;
        Wt[(size_t)n * 512 + k] = f2b(Wd[(size_t)k * 256 + n]);
    }
}

__global__ void k_deg(const int* __restrict__ dst, uint32_t* __restrict__ deg) {
    int e = blockIdx.x * 256 + threadIdx.x;
    if (e < N_EDGES) atomicAdd(&deg[dst[e]], 1u);
}

// ---------- hierarchical exclusive scan over deg ----------
__global__ void k_scan1(const uint32_t* __restrict__ deg, uint32_t* __restrict__ psum) {
    __shared__ uint32_t wsum[4];
    int b = blockIdx.x, t = threadIdx.x;
    int i = b * 256 + t;
    int v = (i < N_NODES) ? (int)deg[i] : 0;
#pragma unroll
    for (int o = 1; o < 64; o <<= 1) v += __shfl_xor(v, o);
    if ((t & 63) == 0) wsum[t >> 6] = (uint32_t)v;
    __syncthreads();
    if (t == 0) psum[b] = wsum[0] + wsum[1] + wsum[2] + wsum[3];
}

// fused scan2+scan3
__global__ void k_scan23(const uint32_t* __restrict__ deg, const uint32_t* __restrict__ psum,
                         uint32_t* __restrict__ off, uint32_t* __restrict__ cur) {
    __shared__ uint32_t sb[256];
    __shared__ uint32_t wsum[4];
    int b = blockIdx.x, t = threadIdx.x;
    int i = b * 256 + t;
    uint32_t pv = (t < b) ? psum[t] : 0u;      // b < 196 <= 256
#pragma unroll
    for (int o = 1; o < 64; o <<= 1) pv += __shfl_xor(pv, o);
    if ((t & 63) == 0) wsum[t >> 6] = pv;
    uint32_t v = (i < N_NODES) ? deg[i] : 0u;
    sb[t] = v;
    __syncthreads();
    uint32_t base = wsum[0] + wsum[1] + wsum[2] + wsum[3];
#pragma unroll
    for (int o = 1; o < 256; o <<= 1) {
        uint32_t u = (t >= o) ? sb[t - o] : 0u;
        __syncthreads();
        sb[t] += u;
        __syncthreads();
    }
    if (i < N_NODES) {
        uint32_t e = base + sb[t] - v;
        off[i] = e;
        cur[i] = e;
    }
    if (b == 0 && t == 0) off[N_NODES] = N_EDGES;
}

__global__ void k_scatter(const int* __restrict__ src, const int* __restrict__ dst,
                          uint32_t* __restrict__ cur, int* __restrict__ esrc) {
    int e = blockIdx.x * 256 + threadIdx.x;
    if (e >= N_EDGES) return;
    int d = dst[e];
    uint32_t pos = atomicAdd(&cur[d], 1u);
    esrc[pos] = src[e];
}

// one wave per node, fp8 gather (1 dword/lane/edge), 8-deep unrolled (R4-proven)
__global__ __launch_bounds__(256) void k_agg(const uint32_t* __restrict__ off,
                                             const int* __restrict__ esrc,
                                             const uint32_t* __restrict__ Xq,
                                             uint16_t* __restrict__ A) {
    int node = blockIdx.x * 4 + (threadIdx.x >> 6);
    if (node >= N_NODES) return;
    int lane = threadIdx.x & 63;
    const uint32_t* Xl = Xq + lane;
    uint32_t s0 = off[node], s1 = off[node + 1];
    float a0 = 0.f, a1 = 0.f, a2 = 0.f, a3 = 0.f;
    uint32_t j = s0;
    for (; j + 8 <= s1; j += 8) {
        int s_[8];
#pragma unroll
        for (int t = 0; t < 8; ++t) s_[t] = esrc[j + t];
        uint32_t w_[8];
#pragma unroll
        for (int t = 0; t < 8; ++t) w_[t] = Xl[(size_t)s_[t] * 64];
#pragma unroll
        for (int t = 0; t < 8; ++t) {
            float f[4];
            unpack4_fp8(w_[t], f);
            a0 += f[0]; a1 += f[1]; a2 += f[2]; a3 += f[3];
        }
    }
    if (j + 4 <= s1) {
        int s_[4];
#pragma unroll
        for (int t = 0; t < 4; ++t) s_[t] = esrc[j + t];
        uint32_t w_[4];
#pragma unroll
        for (int t = 0; t < 4; ++t) w_[t] = Xl[(size_t)s_[t] * 64];
#pragma unroll
        for (int t = 0; t < 4; ++t) {
            float f[4];
            unpack4_fp8(w_[t], f);
            a0 += f[0]; a1 += f[1]; a2 += f[2]; a3 += f[3];
        }
        j += 4;
    }
    for (; j < s1; ++j) {
        uint32_t w0 = Xl[(size_t)esrc[j] * 64];
        float f[4];
        unpack4_fp8(w0, f);
        a0 += f[0]; a1 += f[1]; a2 += f[2]; a3 += f[3];
    }
    float inv = 1.0f / (float)max(s1 - s0, 1u);
    ushort4 o;
    o.x = f2b(a0 * inv); o.y = f2b(a1 * inv); o.z = f2b(a2 * inv); o.w = f2b(a3 * inv);
    *(ushort4*)(A + (size_t)node * 512 + 256 + lane * 4) = o;
}

// ---------- encoder GEMM (R6-proven form) ----------
template <int N, int NY, bool RELU>
__global__ __launch_bounds__(256, 2) void k_gemm_enc(const uint16_t* __restrict__ A,
                                                     const uint16_t* __restrict__ Bt,
                                                     const float* __restrict__ bias,
                                                     float* __restrict__ Cf, int M) {
    constexpr int K = 512;
    constexpr int BK = 64;
    __shared__ __align__(1024) uint16_t As[128 * BK];
    __shared__ __align__(1024) uint16_t Bs[128 * BK];
    const int tid = threadIdx.x;
    const int wave = tid >> 6, lane = tid & 63;
    const int wm = wave >> 1, wn = wave & 1;

    const int nwg = gridDim.x;
    const int bid = blockIdx.x;
    const int xcd = bid & 7, o = bid >> 3;
    const int q = nwg >> 3, r = nwg & 7;
    const int work = (xcd < r ? xcd * (q + 1) : r * (q + 1) + (xcd - r) * q) + o;
    const int m0 = (work / NY) * 128;
    const int n0 = (work % NY) * 128;

    const int l15 = lane & 15, l4 = lane >> 4;

    f32x4 acc[4][4] = {};

    for (int k0 = 0; k0 < K; k0 += BK) {
        __syncthreads();
#pragma unroll
        for (int j = 0; j < 4; ++j) {
            int c = j * 256 + tid;            // 16B chunk id, 0..1023
            int row = c >> 3, p = c & 7;
            int s = p ^ (row & 7);            // pre-swizzled source slot
            int grA = min(m0 + row, M - 1);
            async_copy16(A + (size_t)grA * 512 + k0 + s * 8,
                         (char*)As + j * 4096 + wave * 1024);
            int grB = n0 + row;
            async_copy16(Bt + (size_t)grB * 512 + k0 + s * 8,
                         (char*)Bs + j * 4096 + wave * 1024);
        }
        __syncthreads();
#pragma unroll
        for (int kk = 0; kk < 2; ++kk) {
            bf16x8 af[4], bfr[4];
#pragma unroll
            for (int m = 0; m < 4; ++m) {
                int row = wm * 64 + m * 16 + l15;
                int s = (kk * 4 + l4) ^ (row & 7);
                af[m] = *(const bf16x8*)((const char*)As + row * 128 + s * 16);
            }
#pragma unroll
            for (int n = 0; n < 4; ++n) {
                int row = wn * 64 + n * 16 + l15;
                int s = (kk * 4 + l4) ^ (row & 7);
                bfr[n] = *(const bf16x8*)((const char*)Bs + row * 128 + s * 16);
            }
#pragma unroll
            for (int m = 0; m < 4; ++m)
#pragma unroll
                for (int n = 0; n < 4; ++n)
                    acc[m][n] = __builtin_amdgcn_mfma_f32_16x16x32_bf16(
                        af[m], bfr[n], acc[m][n], 0, 0, 0);
        }
    }

#pragma unroll
    for (int m = 0; m < 4; ++m) {
        int rbase = m0 + wm * 64 + m * 16 + l4 * 4;
#pragma unroll
        for (int i = 0; i < 4; ++i) {
            int r2 = rbase + i;
            if (r2 < M) {
#pragma unroll
                for (int n = 0; n < 4; ++n) {
                    int cidx = n0 + wn * 64 + n * 16 + l15;
                    float v = acc[m][n][i] + bias[cidx];
                    if (RELU) v = fmaxf(v, 0.f);
                    Cf[(size_t)r2 * N + cidx] = v;
                }
            }
        }
    }
}

// ---------- decoder GEMM, retiled: BM=64 x BN=256 (full N), BK=64 ----------
// Grid 782, LDS 40KB, 3 blocks/CU -> ~1 dispatch round. A (f32 out_h) read ONCE,
// reg-staged f32->bf16 (same RNE + same K order -> bit-identical numerics).
__global__ __launch_bounds__(256, 3) void k_gemm_dec2(const float* __restrict__ Af,
                                                      const uint16_t* __restrict__ Bt,
                                                      const float* __restrict__ bias,
                                                      float* __restrict__ Cf, int M) {
    constexpr int K = 512;
    constexpr int N = 256;
    __shared__ __align__(1024) uint16_t As[64 * 64];    //  8 KB
    __shared__ __align__(1024) uint16_t Bs[256 * 64];   // 32 KB
    const int tid = threadIdx.x;
    const int wave = tid >> 6, lane = tid & 63;
    const int wm = wave >> 1, wn = wave & 1;            // wave: 32 rows x 128 cols

    const int nwg = gridDim.x;
    const int bid = blockIdx.x;
    const int xcd = bid & 7, o = bid >> 3;
    const int q = nwg >> 3, r = nwg & 7;
    const int work = (xcd < r ? xcd * (q + 1) : r * (q + 1) + (xcd - r) * q) + o;
    const int m0 = work * 64;

    const int l15 = lane & 15, l4 = lane >> 4;

    f32x4 acc[2][8] = {};

    for (int k0 = 0; k0 < K; k0 += 64) {
        __syncthreads();
        // B: 256 rows x 64 k bf16 = 2048 chunks, 8 per thread, async to LDS
#pragma unroll
        for (int j = 0; j < 8; ++j) {
            int c = j * 256 + tid;
            int row = c >> 3, p = c & 7;
            async_copy16(Bt + (size_t)row * 512 + k0 + ((p ^ (row & 7)) * 8),
                         (char*)Bs + j * 4096 + wave * 1024);
        }
        // A: 64 rows x 64 k f32 -> bf16, 2 chunks per thread, ds_write swizzled
#pragma unroll
        for (int j = 0; j < 2; ++j) {
            int c = j * 256 + tid;
            int row = c >> 3, p = c & 7;
            int grA = min(m0 + row, M - 1);
            const float* srcp = Af + (size_t)grA * 512 + k0 + p * 8;
            float4 v0 = *(const float4*)(srcp);
            float4 v1 = *(const float4*)(srcp + 4);
            uint32_t d0 = (uint32_t)f2b(v0.x) | ((uint32_t)f2b(v0.y) << 16);
            uint32_t d1 = (uint32_t)f2b(v0.z) | ((uint32_t)f2b(v0.w) << 16);
            uint32_t d2 = (uint32_t)f2b(v1.x) | ((uint32_t)f2b(v1.y) << 16);
            uint32_t d3 = (uint32_t)f2b(v1.z) | ((uint32_t)f2b(v1.w) << 16);
            *(uint4*)((char*)As + row * 128 + (p ^ (row & 7)) * 16) =
                make_uint4(d0, d1, d2, d3);
        }
        __syncthreads();
#pragma unroll
        for (int kk = 0; kk < 2; ++kk) {
            bf16x8 af[2], bfr[8];
#pragma unroll
            for (int m = 0; m < 2; ++m) {
                int row = wm * 32 + m * 16 + l15;
                int s = (kk * 4 + l4) ^ (row & 7);
                af[m] = *(const bf16x8*)((const char*)As + row * 128 + s * 16);
            }
#pragma unroll
            for (int n = 0; n < 8; ++n) {
                int row = wn * 128 + n * 16 + l15;
                int s = (kk * 4 + l4) ^ (row & 7);
                bfr[n] = *(const bf16x8*)((const char*)Bs + row * 128 + s * 16);
            }
#pragma unroll
            for (int m = 0; m < 2; ++m)
#pragma unroll
                for (int n = 0; n < 8; ++n)
                    acc[m][n] = __builtin_amdgcn_mfma_f32_16x16x32_bf16(
                        af[m], bfr[n], acc[m][n], 0, 0, 0);
        }
    }

    float bv[8];
#pragma unroll
    for (int n = 0; n < 8; ++n) bv[n] = bias[wn * 128 + n * 16 + l15];

#pragma unroll
    for (int m = 0; m < 2; ++m) {
        int rbase = m0 + wm * 32 + m * 16 + l4 * 4;
#pragma unroll
        for (int i = 0; i < 4; ++i) {
            int r2 = rbase + i;
            if (r2 < M) {
#pragma unroll
                for (int n = 0; n < 8; ++n) {
                    int cidx = wn * 128 + n * 16 + l15;
                    Cf[(size_t)r2 * N + cidx] = acc[m][n][i] + bv[n];
                }
            }
        }
    }
}

// ---------- launch ----------
extern "C" void kernel_launch(void* const* d_in, const int* in_sizes, int n_in,
                              void* d_out, int out_size, void* d_ws, size_t ws_size,
                              hipStream_t stream) {
    const float* x     = (const float*)d_in[0];
    const int*   src   = (const int*)d_in[1];
    const int*   dst   = (const int*)d_in[2];
    const float* Wself = (const float*)d_in[3];
    const float* Wneigh= (const float*)d_in[4];
    const float* benc  = (const float*)d_in[5];
    const float* Wdec  = (const float*)d_in[6];
    const float* bdec  = (const float*)d_in[7];

    float* out_recon = (float*)d_out;                               // [50000*256]
    float* out_h     = (float*)d_out + (size_t)N_NODES * OUT_DIM;   // [50000*512]

    char* ws = (char*)d_ws;
    uint16_t* A    = (uint16_t*)(ws);                    // 51,200,000 B  [50000][512] bf16
    uint16_t* Wc   = (uint16_t*)(ws + 51200000);         //    524,288 B  [512][512] bf16 (W_cat^T)
    uint16_t* Wd   = (uint16_t*)(ws + 51724288);         //    262,144 B  [256][512] bf16 (W_dec^T)
    uint32_t* deg  = (uint32_t*)(ws + 51986432);         //    200,000 B
    uint32_t* off  = (uint32_t*)(ws + 52186432);         //    200,128 B (50001 used)
    uint32_t* cur  = (uint32_t*)(ws + 52386560);         //    200,000 B
    int*     esrc  = (int*)(ws + 52586560);              //  3,200,000 B
    uint32_t* psum = (uint32_t*)(ws + 55786560);         //        784 B
    uint32_t* Xq   = (uint32_t*)(ws + 55788544);         // 12,800,000 B  [50000][64] dwords (fp8 x)

    k_prep<<<14232, 256, 0, stream>>>(x, A, Xq, Wself, Wneigh, Wdec, Wc, Wd, deg);
    k_deg<<<3125, 256, 0, stream>>>(dst, deg);
    k_scan1<<<SCAN_BLOCKS, 256, 0, stream>>>(deg, psum);
    k_scan23<<<SCAN_BLOCKS, 256, 0, stream>>>(deg, psum, off, cur);
    k_scatter<<<3125, 256, 0, stream>>>(src, dst, cur, esrc);
    k_agg<<<12500, 256, 0, stream>>>(off, esrc, Xq, A);
    k_gemm_enc<512, 4, true><<<1564, 256, 0, stream>>>(A, Wc, benc, out_h, N_NODES);
    k_gemm_dec2<<<782, 256, 0, stream>>>(out_h, Wd, bdec, out_recon, N_NODES);
}